// Round 1
// 1091.980 us; speedup vs baseline: 1.0811x; 1.0811x over previous
//
#include <hip/hip_runtime.h>
#include <math.h>

#define NVV 25000
#define NCC 12500
#define NEE 250000
#define KP 160   // padded K for all bf16 GEMM inputs (covers K=128,136,144)

typedef short bf16x8 __attribute__((ext_vector_type(8)));
typedef float f32x4 __attribute__((ext_vector_type(4)));

// ---------- helpers ----------
__device__ __forceinline__ unsigned short f2bf(float f) {  // RNE fp32->bf16
  unsigned u = __float_as_uint(f);
  u += 0x7fffu + ((u >> 16) & 1u);
  return (unsigned short)(u >> 16);
}
__device__ __forceinline__ void gll16(const unsigned short* g, unsigned short* l) {
  __builtin_amdgcn_global_load_lds(
      (const __attribute__((address_space(1))) unsigned int*)(const void*)g,
      (__attribute__((address_space(3))) unsigned int*)(void*)l, 16, 0, 0);
}

// Stage a full 128-row x 160-k bf16 strip (40KB) into LDS in chunk layout
// [kk][row][32]: 10 x global_load_lds_dwordx4 per thread, fully contiguous
// 320B-per-row consumption (no 128B-line over-fetch).
__device__ __forceinline__ void stage_rows(const unsigned short* __restrict__ X,
                                           unsigned short* As, int row0, int N,
                                           int wave, int lane) {
  #pragma unroll
  for (int j = 0; j < 10; ++j) {
    int inst = wave * 10 + j;
    int L = inst * 1024 + lane * 16;                  // byte offset in As
    int kk = L >> 13, r = (L >> 6) & 127, ks = (L & 63) >> 1;
    int grow = row0 + r; if (grow >= N) grow = N - 1;
    gll16(X + (size_t)grow * KP + kk * 32 + ks, As + inst * 512);
  }
}
// Same for a weight matrix WT[128 cols][KP k]; K=160 (5 chunks) variant
__device__ __forceinline__ void stage_w160(const unsigned short* __restrict__ W,
                                           unsigned short* Bs, int wave, int lane) {
  #pragma unroll
  for (int j = 0; j < 10; ++j) {
    int inst = wave * 10 + j;
    int L = inst * 1024 + lane * 16;
    int kk = L >> 13, c = (L >> 6) & 127, ks = (L & 63) >> 1;
    gll16(W + (size_t)c * KP + kk * 32 + ks, Bs + inst * 512);
  }
}
// K=128 (4 chunks) variant for chained stages
__device__ __forceinline__ void stage_w128(const unsigned short* __restrict__ W,
                                           unsigned short* Bs, int wave, int lane) {
  #pragma unroll
  for (int j = 0; j < 8; ++j) {
    int inst = wave * 8 + j;
    int L = inst * 1024 + lane * 16;
    int kk = L >> 13, c = (L >> 6) & 127, ks = (L & 63) >> 1;
    gll16(W + (size_t)c * KP + kk * 32 + ks, Bs + inst * 512);
  }
}

#define ZERO_ACC                                       \
  _Pragma("unroll")                                    \
  for (int mi = 0; mi < 4; ++mi)                       \
    _Pragma("unroll")                                  \
    for (int ni = 0; ni < 4; ++ni) {                   \
      acc[mi][ni][0] = 0.f; acc[mi][ni][1] = 0.f;      \
      acc[mi][ni][2] = 0.f; acc[mi][ni][3] = 0.f; }

#define CHUNK_MFMA(kk)                                                         \
  {                                                                            \
    bf16x8 av[4], bv[4];                                                       \
    _Pragma("unroll")                                                          \
    for (int mi = 0; mi < 4; ++mi)                                             \
      av[mi] = *(const bf16x8*)&As[(kk) * 4096 + (wm + mi * 16 + fr) * 32 + fq * 8]; \
    _Pragma("unroll")                                                          \
    for (int ni = 0; ni < 4; ++ni)                                             \
      bv[ni] = *(const bf16x8*)&Bs[(kk) * 4096 + (wn + ni * 16 + fr) * 32 + fq * 8]; \
    _Pragma("unroll")                                                          \
    for (int mi = 0; mi < 4; ++mi)                                             \
      _Pragma("unroll")                                                        \
      for (int ni = 0; ni < 4; ++ni)                                           \
        acc[mi][ni] = __builtin_amdgcn_mfma_f32_16x16x32_bf16(av[mi], bv[ni],  \
                                                              acc[mi][ni], 0, 0, 0); \
  }

// ---------- bf16 MFMA GEMM: out[N,128] = X[N,160]bf16 @ WT^T ----------
// One-shot A+B staging (full K strip), single barrier, straight MFMA run.
__global__ __launch_bounds__(256) void gemm_mfma(
    const unsigned short* __restrict__ X, const unsigned short* __restrict__ WT,
    const float* __restrict__ bias, float* __restrict__ outf,
    unsigned short* __restrict__ outb, int N, int relu_flag) {
  __shared__ unsigned short As[5 * 128 * 32];   // 40 KB
  __shared__ unsigned short Bs[5 * 128 * 32];   // 40 KB
  const int tid = threadIdx.x;
  const int lane = tid & 63, wave = tid >> 6;
  const int row0 = blockIdx.x * 128;
  const int wm = (wave & 1) * 64, wn = (wave >> 1) * 64;
  const int fr = lane & 15, fq = lane >> 4;

  stage_rows(X, As, row0, N, wave, lane);
  stage_w160(WT, Bs, wave, lane);

  f32x4 acc[4][4];
  ZERO_ACC;
  __syncthreads();           // drains vmcnt(0): all A+B resident
  #pragma unroll
  for (int kk = 0; kk < 5; ++kk) CHUNK_MFMA(kk);

  #pragma unroll
  for (int mi = 0; mi < 4; ++mi) {
    #pragma unroll
    for (int ni = 0; ni < 4; ++ni) {
      int gcol = wn + ni * 16 + fr;
      float bvv = bias ? bias[gcol] : 0.0f;
      #pragma unroll
      for (int r = 0; r < 4; ++r) {
        int grow = row0 + wm + mi * 16 + fq * 4 + r;
        if (grow < N) {
          float o = acc[mi][ni][r] + bvv;
          if (relu_flag) o = fmaxf(o, 0.f);
          if (outf) outf[(size_t)grow * 128 + gcol] = o;
          if (outb) outb[(size_t)grow * 128 + gcol] = f2bf(o);
        }
      }
    }
  }
}

// ---------- chained GEMM: X@W1(+b1,+gather,relu) -> @W2 -> [@W3] ----------
// Each block owns 128 rows x all 128 cols, so stage-k output feeds stage-k+1
// entirely through LDS: intermediate is written bf16 into the As region in the
// chunk layout the fragment reads expect; next-stage weights re-stage into Bs.
__global__ __launch_bounds__(256) void gemm_chain(
    const unsigned short* __restrict__ X,
    const unsigned short* __restrict__ W1, const float* __restrict__ b1,
    const float* __restrict__ gA, const float* __restrict__ gB,
    const int* __restrict__ giA, const int* __restrict__ giB,
    const unsigned short* __restrict__ W2, const float* __restrict__ b2,
    const unsigned short* __restrict__ W3, const float* __restrict__ b3,
    float* __restrict__ outf, int N, int relu_last) {
  __shared__ unsigned short As[5 * 128 * 32];
  __shared__ unsigned short Bs[5 * 128 * 32];
  const int tid = threadIdx.x;
  const int lane = tid & 63, wave = tid >> 6;
  const int row0 = blockIdx.x * 128;
  const int wm = (wave & 1) * 64, wn = (wave >> 1) * 64;
  const int fr = lane & 15, fq = lane >> 4;

  // ---- stage 1 ----
  stage_rows(X, As, row0, N, wave, lane);
  stage_w160(W1, Bs, wave, lane);
  f32x4 acc[4][4];
  ZERO_ACC;
  __syncthreads();
  #pragma unroll
  for (int kk = 0; kk < 5; ++kk) CHUNK_MFMA(kk);

  // ---- epilogue 1 -> T2 (reuse As); W2 -> Bs ----
  __syncthreads();                       // all stage-1 LDS reads finished
  stage_w128(W2, Bs, wave, lane);        // overlaps with gathers below
  #pragma unroll
  for (int mi = 0; mi < 4; ++mi) {
    #pragma unroll
    for (int ni = 0; ni < 4; ++ni) {
      int col = wn + ni * 16 + fr;
      float bvv = b1 ? b1[col] : 0.0f;
      #pragma unroll
      for (int r = 0; r < 4; ++r) {
        int row = wm + mi * 16 + fq * 4 + r;
        int grow = row0 + row;
        int gi = (grow < N) ? grow : (N - 1);
        float o = acc[mi][ni][r] + bvv;
        if (gA) o += gA[(size_t)giA[gi] * 128 + col] + gB[(size_t)giB[gi] * 128 + col];
        o = fmaxf(o, 0.f);
        As[(col >> 5) * 4096 + row * 32 + (col & 31)] = f2bf(o);
      }
    }
  }
  ZERO_ACC;
  __syncthreads();                       // W2 arrived + T2 visible

  // ---- stage 2 ----
  #pragma unroll
  for (int kk = 0; kk < 4; ++kk) CHUNK_MFMA(kk);

  if (W3) {
    // ---- epilogue 2 -> T2; W3 -> Bs ----
    __syncthreads();
    stage_w128(W3, Bs, wave, lane);
    #pragma unroll
    for (int mi = 0; mi < 4; ++mi) {
      #pragma unroll
      for (int ni = 0; ni < 4; ++ni) {
        int col = wn + ni * 16 + fr;
        float bvv = b2 ? b2[col] : 0.0f;
        #pragma unroll
        for (int r = 0; r < 4; ++r) {
          int row = wm + mi * 16 + fq * 4 + r;
          float o = fmaxf(acc[mi][ni][r] + bvv, 0.f);
          As[(col >> 5) * 4096 + row * 32 + (col & 31)] = f2bf(o);
        }
      }
    }
    ZERO_ACC;
    __syncthreads();
    // ---- stage 3 ----
    #pragma unroll
    for (int kk = 0; kk < 4; ++kk) CHUNK_MFMA(kk);
    #pragma unroll
    for (int mi = 0; mi < 4; ++mi) {
      #pragma unroll
      for (int ni = 0; ni < 4; ++ni) {
        int gcol = wn + ni * 16 + fr;
        float bvv = b3 ? b3[gcol] : 0.0f;
        #pragma unroll
        for (int r = 0; r < 4; ++r) {
          int grow = row0 + wm + mi * 16 + fq * 4 + r;
          if (grow < N) {
            float o = acc[mi][ni][r] + bvv;
            if (relu_last) o = fmaxf(o, 0.f);
            outf[(size_t)grow * 128 + gcol] = o;
          }
        }
      }
    }
  } else {
    // ---- final epilogue (2-stage chain) ----
    #pragma unroll
    for (int mi = 0; mi < 4; ++mi) {
      #pragma unroll
      for (int ni = 0; ni < 4; ++ni) {
        int gcol = wn + ni * 16 + fr;
        float bvv = b2 ? b2[gcol] : 0.0f;
        #pragma unroll
        for (int r = 0; r < 4; ++r) {
          int grow = row0 + wm + mi * 16 + fq * 4 + r;
          if (grow < N) {
            float o = acc[mi][ni][r] + bvv;
            if (relu_last) o = fmaxf(o, 0.f);
            outf[(size_t)grow * 128 + gcol] = o;
          }
        }
      }
    }
  }
}

// ---------- build bf16 combined features ----------
__global__ void build_node_bf(const float* __restrict__ learned, const float* __restrict__ lp,
                              unsigned short* __restrict__ out, int N) {
  int idx = blockIdx.x * blockDim.x + threadIdx.x;
  if (idx >= N * 40) return;
  int row = idx / 40, c4 = idx - row * 40;
  int c = c4 * 4;
  ushort4 o;
  if (c4 < 32) {
    const float* p = learned + (size_t)row * 128 + c;
    o.x = f2bf(p[0]); o.y = f2bf(p[1]); o.z = f2bf(p[2]); o.w = f2bf(p[3]);
  } else if (c4 < 36) {
    const float* p = lp + (size_t)row * 16 + (c - 128);
    o.x = f2bf(p[0]); o.y = f2bf(p[1]); o.z = f2bf(p[2]); o.w = f2bf(p[3]);
  } else { o.x = o.y = o.z = o.w = 0; }
  *(ushort4*)&out[(size_t)row * KP + c] = o;
}

__global__ void build_edge_bf(const float* __restrict__ el, const float* __restrict__ lo,
                              const float* __restrict__ hi, const float* __restrict__ dm,
                              const float* __restrict__ wo, unsigned short* __restrict__ out) {
  int idx = blockIdx.x * blockDim.x + threadIdx.x;
  if (idx >= NEE * 40) return;
  int row = idx / 40, c4 = idx - row * 40;
  int c = c4 * 4;
  ushort4 o;
  if (c4 < 32) {
    const float* p = el + (size_t)row * 128 + c;
    o.x = f2bf(p[0]); o.y = f2bf(p[1]); o.z = f2bf(p[2]); o.w = f2bf(p[3]);
  } else if (c4 == 32) {
    o.x = f2bf(lo[row]); o.y = f2bf(hi[row]); o.z = f2bf(dm[row]);
    o.w = f2bf(wo[(size_t)row * 5 + 0]);
  } else if (c4 == 33) {
    const float* p = wo + (size_t)row * 5;
    o.x = f2bf(p[1]); o.y = f2bf(p[2]); o.z = f2bf(p[3]); o.w = f2bf(p[4]);
  } else { o.x = o.y = o.z = o.w = 0; }
  *(ushort4*)&out[(size_t)row * KP + c] = o;
}

// ---------- weight transpose + convert ----------
struct WJobs {
  const float* W[18];
  unsigned short* O[18];
  int K[18];
};
__global__ void convert_weights(WJobs j) {
  int b = blockIdx.x;
  int job = b / 80;
  int i = (b - job * 80) * 256 + threadIdx.x;
  int col = i / KP;
  int k = i - col * KP;
  int K = j.K[job];
  j.O[job][(size_t)col * KP + k] =
      (k < K) ? f2bf(j.W[job][(size_t)k * 128 + col]) : (unsigned short)0;
}

// ---------- CSR construction ----------
__global__ void zero2(int* __restrict__ a, int na, int* __restrict__ b, int nb) {
  int i = blockIdx.x * blockDim.x + threadIdx.x;
  if (i < na) a[i] = 0;
  if (i < nb) b[i] = 0;
}
__global__ void hist2(const int* __restrict__ dc, int* __restrict__ cc,
                      const int* __restrict__ dv, int* __restrict__ cv, int nE) {
  int e = blockIdx.x * blockDim.x + threadIdx.x;
  if (e >= nE) return;
  atomicAdd(&cc[dc[e]], 1);
  atomicAdd(&cv[dv[e]], 1);
}
// single block 256 threads
__global__ void csr_scan(const int* __restrict__ counts, int* __restrict__ offsets,
                         int* __restrict__ cursor, int n) {
  __shared__ int part[256];
  int tid = threadIdx.x;
  int chunk = (n + 255) / 256;
  int lo = tid * chunk, hi = min(n, lo + chunk);
  int s = 0;
  for (int i = lo; i < hi; ++i) s += counts[i];
  part[tid] = s;
  __syncthreads();
  if (tid == 0) {
    int run = 0;
    for (int i = 0; i < 256; ++i) { int t = part[i]; part[i] = run; run += t; }
    offsets[n] = run;
  }
  __syncthreads();
  int base = part[tid];
  for (int i = lo; i < hi; ++i) { offsets[i] = base; cursor[i] = base; base += counts[i]; }
}
__global__ void csr_scatter(const int* __restrict__ dst, const int* __restrict__ src,
                            int* __restrict__ cursor, int* __restrict__ ce,
                            int* __restrict__ cs, int nE) {
  int e = blockIdx.x * blockDim.x + threadIdx.x;
  if (e >= nE) return;
  int pos = atomicAdd(&cursor[dst[e]], 1);
  ce[pos] = e;
  cs[pos] = src[e];
}

// ---------- fused flash-style segment attention: one wave per dst ----------
__global__ __launch_bounds__(256) void fused_attn(
    const float* __restrict__ qbuf, const float* __restrict__ kbuf,
    const float* __restrict__ vbuf, const unsigned short* __restrict__ ee,
    const int* __restrict__ offsets, const int* __restrict__ ce,
    const int* __restrict__ cs, const float* __restrict__ skip,
    float* __restrict__ outd, unsigned short* __restrict__ comb, int Nd) {
  int d = blockIdx.x * 4 + (threadIdx.x >> 6);
  if (d >= Nd) return;
  int lane = threadIdx.x & 63;
  int c = lane * 2;
  float2 qv = *(const float2*)&qbuf[(size_t)d * 128 + c];
  int beg = offsets[d], end = offsets[d + 1];
  float m = -INFINITY, l = 0.f;
  float ax = 0.f, ay = 0.f;
  for (int i = beg; i < end; ++i) {
    int e = ce[i], s = cs[i];
    unsigned eu = *(const unsigned*)&ee[(size_t)e * 128 + c];
    float e0 = __uint_as_float(eu << 16);
    float e1 = __uint_as_float(eu & 0xffff0000u);
    float2 kv = *(const float2*)&kbuf[(size_t)s * 128 + c];
    float2 vv = *(const float2*)&vbuf[(size_t)s * 128 + c];
    float p = qv.x * (kv.x + e0) + qv.y * (kv.y + e1);
    #pragma unroll
    for (int off = 1; off < 64; off <<= 1) p += __shfl_xor(p, off, 64);
    float alpha = p * 0.08838834764831845f;  // 1/sqrt(128)
    float mn = fmaxf(m, alpha);
    float scale = __expf(m - mn);            // first iter: exp(-inf)=0
    float w = __expf(alpha - mn);
    ax = ax * scale + (vv.x + e0) * w;
    ay = ay * scale + (vv.y + e1) * w;
    l = l * scale + w;
    m = mn;
  }
  int deg = end - beg;
  float inv = (deg > 0) ? 1.0f / (l * (float)deg) : 0.0f;
  float2 sk = *(const float2*)&skip[(size_t)d * 128 + c];
  float o0 = fmaxf(ax * inv + sk.x, 0.f);
  float o1 = fmaxf(ay * inv + sk.y, 0.f);
  *(float2*)&outd[(size_t)d * 128 + c] = make_float2(o0, o1);
  ushort2 ob; ob.x = f2bf(o0); ob.y = f2bf(o1);
  *(ushort2*)&comb[(size_t)d * KP + c] = ob;
}

static inline void gemm(const unsigned short* X, const unsigned short* WT, const float* bias,
                        float* outf, unsigned short* outb, int N, int relu, hipStream_t s) {
  gemm_mfma<<<(N + 127) / 128, 256, 0, s>>>(X, WT, bias, outf, outb, N, relu);
}

extern "C" void kernel_launch(void* const* d_in, const int* in_sizes, int n_in,
                              void* d_out, int out_size, void* d_ws, size_t ws_size,
                              hipStream_t stream) {
  const float* var_learned = (const float*)d_in[0];
  const float* var_lp      = (const float*)d_in[1];
  const float* con_learned = (const float*)d_in[2];
  const float* con_lp      = (const float*)d_in[3];
  const float* edge_learned= (const float*)d_in[4];
  const float* lo          = (const float*)d_in[5];
  const float* hi          = (const float*)d_in[6];
  const float* dm          = (const float*)d_in[7];
  const float* wo          = (const float*)d_in[8];
  const float* cu_Wq = (const float*)d_in[9],  *cu_bq = (const float*)d_in[10];
  const float* cu_Wk = (const float*)d_in[11], *cu_bk = (const float*)d_in[12];
  const float* cu_Wv = (const float*)d_in[13], *cu_bv = (const float*)d_in[14];
  const float* cu_We = (const float*)d_in[15];
  const float* cu_Ws = (const float*)d_in[16], *cu_bs = (const float*)d_in[17];
  const float* vu_Wq = (const float*)d_in[18], *vu_bq = (const float*)d_in[19];
  const float* vu_Wk = (const float*)d_in[20], *vu_bk = (const float*)d_in[21];
  const float* vu_Wv = (const float*)d_in[22], *vu_bv = (const float*)d_in[23];
  const float* vu_We = (const float*)d_in[24];
  const float* vu_Ws = (const float*)d_in[25], *vu_bs = (const float*)d_in[26];
  const float* eu_vW1 = (const float*)d_in[27], *eu_vb1 = (const float*)d_in[28];
  const float* eu_vW2 = (const float*)d_in[29], *eu_vb2 = (const float*)d_in[30];
  const float* eu_cW1 = (const float*)d_in[31], *eu_cb1 = (const float*)d_in[32];
  const float* eu_cW2 = (const float*)d_in[33], *eu_cb2 = (const float*)d_in[34];
  const float* eu_eW1 = (const float*)d_in[35], *eu_eb1 = (const float*)d_in[36];
  const float* eu_eW2 = (const float*)d_in[37], *eu_eb2 = (const float*)d_in[38];
  const int* eiv = (const int*)d_in[39];
  const int* eic = (const int*)d_in[40];

  float* out_var  = (float*)d_out;
  float* out_con  = out_var + (size_t)NVV * 128;
  float* out_edge = out_con + (size_t)NCC * 128;

  // ---- workspace arena ----
  char* w = (char*)d_ws;
  auto alloc = [&](size_t bytes) { char* p = w; w += (bytes + 255) & ~(size_t)255; return p; };
  unsigned short* edge_comb_bf = (unsigned short*)alloc((size_t)NEE * KP * 2);
  unsigned short* ee_bf = (unsigned short*)alloc((size_t)NEE * 128 * 2);
  unsigned short* var_comb_bf = (unsigned short*)alloc((size_t)NVV * KP * 2);
  unsigned short* con_comb_bf = (unsigned short*)alloc((size_t)NCC * KP * 2);
  float* bufV1 = (float*)alloc((size_t)NVV * 128 * 4);
  float* bufV2 = (float*)alloc((size_t)NVV * 128 * 4);
  float* bufC1 = (float*)alloc((size_t)NCC * 128 * 4);
  float* bufC2 = (float*)alloc((size_t)NCC * 128 * 4);
  unsigned short* WTbase = (unsigned short*)alloc((size_t)18 * 128 * KP * 2);
  int* countsC = (int*)alloc((size_t)NCC * 4);
  int* countsV = (int*)alloc((size_t)NVV * 4);
  int* offC = (int*)alloc((size_t)(NCC + 1) * 4);
  int* curC = (int*)alloc((size_t)NCC * 4);
  int* offV = (int*)alloc((size_t)(NVV + 1) * 4);
  int* curV = (int*)alloc((size_t)NVV * 4);
  int* ceA = (int*)alloc((size_t)NEE * 4);  // conv A (dst=con): edge ids
  int* csA = (int*)alloc((size_t)NEE * 4);  //                   src (var) ids
  int* ceB = (int*)alloc((size_t)NEE * 4);  // conv B (dst=var)
  int* csB = (int*)alloc((size_t)NEE * 4);
  (void)ws_size; (void)in_sizes; (void)n_in; (void)out_size;

  unsigned short* WT[18];
  for (int i = 0; i < 18; ++i) WT[i] = WTbase + (size_t)i * 128 * KP;
  WJobs jobs;
  const float* Wsrc[18] = {cu_Wq, cu_Wk, cu_Wv, cu_We, cu_Ws,
                           vu_Wq, vu_Wk, vu_Wv, vu_We, vu_Ws,
                           eu_vW1, eu_vW2, eu_cW1, eu_cW2,
                           eu_eW1, eu_eW1 + 136 * 128, eu_eW1 + 264 * 128, eu_eW2};
  const int Ksrc[18] = {144, 144, 144, 136, 144, 144, 144, 144, 136, 144,
                        144, 128, 144, 128, 136, 128, 128, 128};
  for (int i = 0; i < 18; ++i) { jobs.W[i] = Wsrc[i]; jobs.O[i] = WT[i]; jobs.K[i] = Ksrc[i]; }

  const int T = 256;

  // ---- pre-passes ----
  build_node_bf<<<(NVV * 40 + T - 1) / T, T, 0, stream>>>(var_learned, var_lp, var_comb_bf, NVV);
  build_node_bf<<<(NCC * 40 + T - 1) / T, T, 0, stream>>>(con_learned, con_lp, con_comb_bf, NCC);
  build_edge_bf<<<(NEE * 40 + T - 1) / T, T, 0, stream>>>(edge_learned, lo, hi, dm, wo, edge_comb_bf);
  convert_weights<<<18 * 80, T, 0, stream>>>(jobs);

  // ---- CSR builds (both convs; independent of GEMMs) ----
  zero2<<<(NVV + T - 1) / T, T, 0, stream>>>(countsC, NCC, countsV, NVV);
  hist2<<<(NEE + T - 1) / T, T, 0, stream>>>(eic, countsC, eiv, countsV, NEE);
  csr_scan<<<1, 256, 0, stream>>>(countsC, offC, curC, NCC);
  csr_scan<<<1, 256, 0, stream>>>(countsV, offV, curV, NVV);
  csr_scatter<<<(NEE + T - 1) / T, T, 0, stream>>>(eic, eiv, curC, ceA, csA, NEE);
  csr_scatter<<<(NEE + T - 1) / T, T, 0, stream>>>(eiv, eic, curV, ceB, csB, NEE);

  // ================= Stage A: con update (src=var, dst=con) =================
  gemm(con_comb_bf, WT[0], cu_bq, bufC1, nullptr, NCC, 0, stream); // q_c
  gemm(con_comb_bf, WT[4], cu_bs, bufC2, nullptr, NCC, 0, stream); // skip_c
  gemm(var_comb_bf, WT[1], cu_bk, bufV1, nullptr, NVV, 0, stream); // k_v
  gemm(var_comb_bf, WT[2], cu_bv, bufV2, nullptr, NVV, 0, stream); // v_v
  gemm(edge_comb_bf, WT[3], nullptr, nullptr, ee_bf, NEE, 0, stream); // ee bf16
  fused_attn<<<(NCC + 3) / 4, 256, 0, stream>>>(bufC1, bufV1, bufV2, ee_bf, offC, ceA, csA,
                                                bufC2, out_con, con_comb_bf, NCC);

  // ================= Stage B: var update (src=new con, dst=var) =================
  gemm(var_comb_bf, WT[5], vu_bq, bufV1, nullptr, NVV, 0, stream); // q_v
  gemm(var_comb_bf, WT[9], vu_bs, bufV2, nullptr, NVV, 0, stream); // skip_v
  gemm(con_comb_bf, WT[6], vu_bk, bufC1, nullptr, NCC, 0, stream); // k_c
  gemm(con_comb_bf, WT[7], vu_bv, bufC2, nullptr, NCC, 0, stream); // v_c
  gemm(edge_comb_bf, WT[8], nullptr, nullptr, ee_bf, NEE, 0, stream); // ee2 bf16
  fused_attn<<<(NVV + 3) / 4, 256, 0, stream>>>(bufV1, bufC1, bufC2, ee_bf, offV, ceB, csB,
                                                bufV2, out_var, var_comb_bf, NVV);

  // ================= Edge stage (fully chained) =================
  // vcW = (relu(relu(var_comb@vW1+b1)@vW2+b2)) @ eW1[136:264]   (3-stage chain)
  gemm_chain<<<(NVV + 127) / 128, 256, 0, stream>>>(
      var_comb_bf, WT[10], eu_vb1, nullptr, nullptr, nullptr, nullptr,
      WT[11], eu_vb2, WT[15], nullptr, bufV1, NVV, 0);
  // ccW = (relu(relu(con_comb@cW1+b1)@cW2+b2)) @ eW1[264:392]   (3-stage chain)
  gemm_chain<<<(NCC + 127) / 128, 256, 0, stream>>>(
      con_comb_bf, WT[12], eu_cb1, nullptr, nullptr, nullptr, nullptr,
      WT[13], eu_cb2, WT[16], nullptr, bufC1, NCC, 0);
  // edge_new = relu( relu(edge_comb@eW1[0:136] + vcW[eiv] + ccW[eic] + b1) @ eW2 + b2 )
  gemm_chain<<<(NEE + 127) / 128, 256, 0, stream>>>(
      edge_comb_bf, WT[14], eu_eb1, bufV1, bufC1, eiv, eic,
      WT[17], eu_eb2, nullptr, nullptr, out_edge, NEE, 1);
}

// Round 2
// 1006.404 us; speedup vs baseline: 1.1730x; 1.0850x over previous
//
#include <hip/hip_runtime.h>
#include <math.h>

#define NVV 25000
#define NCC 12500
#define NEE 250000
#define KP 160   // padded K for all bf16 GEMM inputs (covers K=128,136,144)

typedef short bf16x8 __attribute__((ext_vector_type(8)));
typedef float f32x4 __attribute__((ext_vector_type(4)));

// ---------- helpers ----------
__device__ __forceinline__ unsigned short f2bf(float f) {  // RNE fp32->bf16
  unsigned u = __float_as_uint(f);
  u += 0x7fffu + ((u >> 16) & 1u);
  return (unsigned short)(u >> 16);
}
__device__ __forceinline__ void gll16(const unsigned short* g, unsigned short* l) {
  __builtin_amdgcn_global_load_lds(
      (const __attribute__((address_space(1))) unsigned int*)(const void*)g,
      (__attribute__((address_space(3))) unsigned int*)(void*)l, 16, 0, 0);
}

// Stage a full 128-row x 160-k bf16 strip (40KB) into LDS chunk layout
// [kk][row][32]: 10 x global_load_lds_dwordx4 per thread, fully contiguous
// 320B-per-row consumption.
__device__ __forceinline__ void stage_rows(const unsigned short* __restrict__ X,
                                           unsigned short* As, int row0, int N,
                                           int wave, int lane) {
  #pragma unroll
  for (int j = 0; j < 10; ++j) {
    int inst = wave * 10 + j;
    int L = inst * 1024 + lane * 16;                  // byte offset in As
    int kk = L >> 13, r = (L >> 6) & 127, ks = (L & 63) >> 1;
    int grow = row0 + r; if (grow >= N) grow = N - 1;
    gll16(X + (size_t)grow * KP + kk * 32 + ks, As + inst * 512);
  }
}

template <int NI>
__device__ __forceinline__ void zero_acc(f32x4 (&acc)[4][NI]) {
  #pragma unroll
  for (int mi = 0; mi < 4; ++mi)
    #pragma unroll
    for (int ni = 0; ni < NI; ++ni) {
      acc[mi][ni][0] = 0.f; acc[mi][ni][1] = 0.f;
      acc[mi][ni][2] = 0.f; acc[mi][ni][3] = 0.f;
    }
}

// One K-chunk (32) of MFMA: A fragments from LDS, B fragments straight from
// global (weights are a 40KB L2-hot table shared by all blocks).
template <int NI>
__device__ __forceinline__ void chunk_mfma_g(const unsigned short* As,
                                             const unsigned short* __restrict__ WT,
                                             f32x4 (&acc)[4][NI], int kk,
                                             int wm, int wn, int fr, int fq) {
  bf16x8 av[4], bv[NI];
  #pragma unroll
  for (int mi = 0; mi < 4; ++mi)
    av[mi] = *(const bf16x8*)&As[kk * 4096 + (wm + mi * 16 + fr) * 32 + fq * 8];
  #pragma unroll
  for (int ni = 0; ni < NI; ++ni)
    bv[ni] = *(const bf16x8*)&WT[(size_t)(wn + ni * 16 + fr) * KP + kk * 32 + fq * 8];
  #pragma unroll
  for (int mi = 0; mi < 4; ++mi)
    #pragma unroll
    for (int ni = 0; ni < NI; ++ni)
      acc[mi][ni] = __builtin_amdgcn_mfma_f32_16x16x32_bf16(av[mi], bv[ni],
                                                            acc[mi][ni], 0, 0, 0);
}

// ---------- batched bf16 MFMA GEMM: out[N,128] = X[N,160] @ WT^T ----------
struct GJob {
  const unsigned short* X; const unsigned short* WT;
  const float* bias; const float* addf;
  float* outf; unsigned short* outb;
  int outb_stride, pad_flag, N, relu_flag;
};
struct GBatch { GJob j[4]; int start[4]; int njobs; };

__global__ __launch_bounds__(256, 4) void gemm_batch(GBatch B) {
  int job = 0;
  #pragma unroll
  for (int t = 1; t < 4; ++t)
    if (t < B.njobs && (int)blockIdx.x >= B.start[t]) job = t;
  GJob g = B.j[job];
  __shared__ unsigned short As[5 * 128 * 32];   // 40 KB
  const int tid = threadIdx.x;
  const int lane = tid & 63, wave = tid >> 6;
  const int row0 = (blockIdx.x - B.start[job]) * 128;
  const int wm = (wave & 1) * 64, wn = (wave >> 1) * 64;
  const int fr = lane & 15, fq = lane >> 4;

  stage_rows(g.X, As, row0, g.N, wave, lane);
  f32x4 acc[4][4];
  zero_acc<4>(acc);
  __syncthreads();
  #pragma unroll
  for (int kk = 0; kk < 5; ++kk) chunk_mfma_g<4>(As, g.WT, acc, kk, wm, wn, fr, fq);

  #pragma unroll
  for (int mi = 0; mi < 4; ++mi) {
    #pragma unroll
    for (int ni = 0; ni < 4; ++ni) {
      int gcol = wn + ni * 16 + fr;
      float bvv = g.bias ? g.bias[gcol] : 0.0f;
      #pragma unroll
      for (int r = 0; r < 4; ++r) {
        int grow = row0 + wm + mi * 16 + fq * 4 + r;
        if (grow < g.N) {
          float o = acc[mi][ni][r] + bvv;
          if (g.addf) o += g.addf[(size_t)grow * 128 + gcol];
          if (g.relu_flag) o = fmaxf(o, 0.f);
          if (g.outf) outf_store: g.outf[(size_t)grow * 128 + gcol] = o;
          if (g.outb) g.outb[(size_t)grow * g.outb_stride + gcol] = f2bf(o);
        }
      }
    }
    if (g.outb && g.pad_flag && wn == 0) {
      #pragma unroll
      for (int r = 0; r < 4; ++r) {
        int grow = row0 + wm + mi * 16 + fq * 4 + r;
        if (grow < g.N)
          for (int pc = 128 + fr; pc < g.outb_stride; pc += 16)
            g.outb[(size_t)grow * g.outb_stride + pc] = 0;
      }
    }
  }
}

// ---------- NI=5 GEMM: t[N,160] = X[N,160(K=128)] @ W'[160,K], bf16 out ----
__global__ __launch_bounds__(256, 2) void gemm_t(
    const unsigned short* __restrict__ X, const unsigned short* __restrict__ WT,
    unsigned short* __restrict__ outb, int N) {
  __shared__ unsigned short As[5 * 128 * 32];
  const int tid = threadIdx.x;
  const int lane = tid & 63, wave = tid >> 6;
  const int row0 = blockIdx.x * 128;
  const int wm = (wave & 1) * 64, wn = (wave >> 1) * 80;
  const int fr = lane & 15, fq = lane >> 4;

  stage_rows(X, As, row0, N, wave, lane);
  f32x4 acc[4][5];
  zero_acc<5>(acc);
  __syncthreads();
  #pragma unroll
  for (int kk = 0; kk < 5; ++kk) chunk_mfma_g<5>(As, WT, acc, kk, wm, wn, fr, fq);

  #pragma unroll
  for (int mi = 0; mi < 4; ++mi)
    #pragma unroll
    for (int ni = 0; ni < 5; ++ni) {
      int gcol = wn + ni * 16 + fr;
      #pragma unroll
      for (int r = 0; r < 4; ++r) {
        int grow = row0 + wm + mi * 16 + fq * 4 + r;
        if (grow < N) outb[(size_t)grow * KP + gcol] = f2bf(acc[mi][ni][r]);
      }
    }
}

// ---------- chained GEMM: X@W1(+b1,+gather,relu) -> @W2 -> [@W3] ----------
__global__ __launch_bounds__(256, 3) void gemm_chain(
    const unsigned short* __restrict__ X,
    const unsigned short* __restrict__ W1, const float* __restrict__ b1,
    const float* __restrict__ gA, const float* __restrict__ gB,
    const int* __restrict__ giA, const int* __restrict__ giB,
    const unsigned short* __restrict__ W2, const float* __restrict__ b2,
    const unsigned short* __restrict__ W3, const float* __restrict__ b3,
    float* __restrict__ outf, int N, int relu_last) {
  __shared__ unsigned short As[5 * 128 * 32];   // 40 KB, reused for T2
  const int tid = threadIdx.x;
  const int lane = tid & 63, wave = tid >> 6;
  const int row0 = blockIdx.x * 128;
  const int wm = (wave & 1) * 64, wn = (wave >> 1) * 64;
  const int fr = lane & 15, fq = lane >> 4;

  // ---- stage 1 ----
  stage_rows(X, As, row0, N, wave, lane);
  f32x4 acc[4][4];
  zero_acc<4>(acc);
  __syncthreads();
  #pragma unroll
  for (int kk = 0; kk < 5; ++kk) chunk_mfma_g<4>(As, W1, acc, kk, wm, wn, fr, fq);

  // ---- epilogue 1 -> T2 (reuse As) ----
  __syncthreads();                       // all stage-1 LDS reads finished
  #pragma unroll
  for (int mi = 0; mi < 4; ++mi) {
    #pragma unroll
    for (int ni = 0; ni < 4; ++ni) {
      int col = wn + ni * 16 + fr;
      float bvv = b1 ? b1[col] : 0.0f;
      #pragma unroll
      for (int r = 0; r < 4; ++r) {
        int row = wm + mi * 16 + fq * 4 + r;
        int grow = row0 + row;
        int gi = (grow < N) ? grow : (N - 1);
        float o = acc[mi][ni][r] + bvv;
        if (gA) o += gA[(size_t)giA[gi] * 128 + col] + gB[(size_t)giB[gi] * 128 + col];
        o = fmaxf(o, 0.f);
        As[(col >> 5) * 4096 + row * 32 + (col & 31)] = f2bf(o);
      }
    }
  }
  zero_acc<4>(acc);
  __syncthreads();                       // T2 visible

  // ---- stage 2 ----
  #pragma unroll
  for (int kk = 0; kk < 4; ++kk) chunk_mfma_g<4>(As, W2, acc, kk, wm, wn, fr, fq);

  if (W3) {
    __syncthreads();
    #pragma unroll
    for (int mi = 0; mi < 4; ++mi) {
      #pragma unroll
      for (int ni = 0; ni < 4; ++ni) {
        int col = wn + ni * 16 + fr;
        float bvv = b2 ? b2[col] : 0.0f;
        #pragma unroll
        for (int r = 0; r < 4; ++r) {
          int row = wm + mi * 16 + fq * 4 + r;
          float o = fmaxf(acc[mi][ni][r] + bvv, 0.f);
          As[(col >> 5) * 4096 + row * 32 + (col & 31)] = f2bf(o);
        }
      }
    }
    zero_acc<4>(acc);
    __syncthreads();
    #pragma unroll
    for (int kk = 0; kk < 4; ++kk) chunk_mfma_g<4>(As, W3, acc, kk, wm, wn, fr, fq);
    #pragma unroll
    for (int mi = 0; mi < 4; ++mi)
      #pragma unroll
      for (int ni = 0; ni < 4; ++ni) {
        int gcol = wn + ni * 16 + fr;
        float bvv = b3 ? b3[gcol] : 0.0f;
        #pragma unroll
        for (int r = 0; r < 4; ++r) {
          int grow = row0 + wm + mi * 16 + fq * 4 + r;
          if (grow < N) {
            float o = acc[mi][ni][r] + bvv;
            if (relu_last) o = fmaxf(o, 0.f);
            outf[(size_t)grow * 128 + gcol] = o;
          }
        }
      }
  } else {
    #pragma unroll
    for (int mi = 0; mi < 4; ++mi)
      #pragma unroll
      for (int ni = 0; ni < 4; ++ni) {
        int gcol = wn + ni * 16 + fr;
        float bvv = b2 ? b2[gcol] : 0.0f;
        #pragma unroll
        for (int r = 0; r < 4; ++r) {
          int grow = row0 + wm + mi * 16 + fq * 4 + r;
          if (grow < N) {
            float o = acc[mi][ni][r] + bvv;
            if (relu_last) o = fmaxf(o, 0.f);
            outf[(size_t)grow * 128 + gcol] = o;
          }
        }
      }
  }
}

// ---------- build bf16 combined features ----------
__global__ void build_node_bf(const float* __restrict__ learned, const float* __restrict__ lp,
                              unsigned short* __restrict__ out, int N) {
  int idx = blockIdx.x * blockDim.x + threadIdx.x;
  if (idx >= N * 40) return;
  int row = idx / 40, c4 = idx - row * 40;
  int c = c4 * 4;
  ushort4 o;
  if (c4 < 32) {
    const float* p = learned + (size_t)row * 128 + c;
    o.x = f2bf(p[0]); o.y = f2bf(p[1]); o.z = f2bf(p[2]); o.w = f2bf(p[3]);
  } else if (c4 < 36) {
    const float* p = lp + (size_t)row * 16 + (c - 128);
    o.x = f2bf(p[0]); o.y = f2bf(p[1]); o.z = f2bf(p[2]); o.w = f2bf(p[3]);
  } else { o.x = o.y = o.z = o.w = 0; }
  *(ushort4*)&out[(size_t)row * KP + c] = o;
}

__global__ void build_edge_bf(const float* __restrict__ el, const float* __restrict__ lo,
                              const float* __restrict__ hi, const float* __restrict__ dm,
                              const float* __restrict__ wo, unsigned short* __restrict__ out) {
  int idx = blockIdx.x * blockDim.x + threadIdx.x;
  if (idx >= NEE * 40) return;
  int row = idx / 40, c4 = idx - row * 40;
  int c = c4 * 4;
  ushort4 o;
  if (c4 < 32) {
    const float* p = el + (size_t)row * 128 + c;
    o.x = f2bf(p[0]); o.y = f2bf(p[1]); o.z = f2bf(p[2]); o.w = f2bf(p[3]);
  } else if (c4 == 32) {
    o.x = f2bf(lo[row]); o.y = f2bf(hi[row]); o.z = f2bf(dm[row]);
    o.w = f2bf(wo[(size_t)row * 5 + 0]);
  } else if (c4 == 33) {
    const float* p = wo + (size_t)row * 5;
    o.x = f2bf(p[1]); o.y = f2bf(p[2]); o.z = f2bf(p[3]); o.w = f2bf(p[4]);
  } else { o.x = o.y = o.z = o.w = 0; }
  *(ushort4*)&out[(size_t)row * KP + c] = o;
}

// ---------- weight transpose/copy + convert ----------
// TR=1: O[col][k] = W[k,col] (col<128, k<K)     — GEMM weight layout
// TR=0: O[i][o]   = W[i,o]   (i<136, o<K=128)   — straight copy (We for t-GEMM)
struct WJobs {
  const float* W[20];
  unsigned short* O[20];
  int K[20];
  int TR[20];
};
__global__ void convert_weights(WJobs j) {
  int b = blockIdx.x;
  int job = b / 100;
  int i = (b - job * 100) * 256 + threadIdx.x;   // 0 .. 160*KP
  int col = i / KP;
  int k = i - col * KP;
  float v = 0.f;
  if (j.TR[job]) { if (col < 128 && k < j.K[job]) v = j.W[job][(size_t)k * 128 + col]; }
  else           { if (col < 136 && k < j.K[job]) v = j.W[job][(size_t)col * 128 + k]; }
  j.O[job][(size_t)col * KP + k] = f2bf(v);
}

// ---------- CSR construction ----------
__global__ void zero2(int* __restrict__ a, int na, int* __restrict__ b, int nb) {
  int i = blockIdx.x * blockDim.x + threadIdx.x;
  if (i < na) a[i] = 0;
  if (i < nb) b[i] = 0;
}
__global__ void hist2(const int* __restrict__ dc, int* __restrict__ cc,
                      const int* __restrict__ dv, int* __restrict__ cv, int nE) {
  int e = blockIdx.x * blockDim.x + threadIdx.x;
  if (e >= nE) return;
  atomicAdd(&cc[dc[e]], 1);
  atomicAdd(&cv[dv[e]], 1);
}
// single block 256 threads
__global__ void csr_scan(const int* __restrict__ counts, int* __restrict__ offsets,
                         int* __restrict__ cursor, int n) {
  __shared__ int part[256];
  int tid = threadIdx.x;
  int chunk = (n + 255) / 256;
  int lo = tid * chunk, hi = min(n, lo + chunk);
  int s = 0;
  for (int i = lo; i < hi; ++i) s += counts[i];
  part[tid] = s;
  __syncthreads();
  if (tid == 0) {
    int run = 0;
    for (int i = 0; i < 256; ++i) { int t = part[i]; part[i] = run; run += t; }
    offsets[n] = run;
  }
  __syncthreads();
  int base = part[tid];
  for (int i = lo; i < hi; ++i) { offsets[i] = base; cursor[i] = base; base += counts[i]; }
}
__global__ void csr_scatter(const int* __restrict__ dst, const int* __restrict__ src,
                            int* __restrict__ cursor, int* __restrict__ ce,
                            int* __restrict__ cs, int nE) {
  int e = blockIdx.x * blockDim.x + threadIdx.x;
  if (e >= nE) return;
  int pos = atomicAdd(&cursor[dst[e]], 1);
  ce[pos] = e;
  cs[pos] = src[e];
}

// ---------- fused flash-style segment attention: one wave per dst ----------
// ee eliminated algebraically:  q·ee = t·e with t = We@q (bf16, [Nd,160]);
// Σ a·ee = (Σ a·e)@We  -> accumulate 136-dim weighted edge sum, transform later.
// Outputs: accVS[d] = acc_v*inv + skip  (f32, in-place over skip buffer)
//          accE[d]  = (Σ w·e)*inv      (bf16, KP stride, cols 136..159 = 0)
__global__ __launch_bounds__(256) void fused_attn(
    const float* __restrict__ qbuf, const float* __restrict__ kbuf,
    const float* __restrict__ vbuf, const unsigned short* __restrict__ tbuf,
    const unsigned short* __restrict__ ecomb,
    const int* __restrict__ offsets, const int* __restrict__ ce,
    const int* __restrict__ cs, float* __restrict__ accVS,
    unsigned short* __restrict__ accE, int Nd) {
  int d = blockIdx.x * 4 + (threadIdx.x >> 6);
  if (d >= Nd) return;
  int lane = threadIdx.x & 63;
  int c = lane * 2;
  bool tl = (lane < 16);
  int c2 = 128 + c;                     // tail cols for lanes 0..15
  float2 qv = *(const float2*)&qbuf[(size_t)d * 128 + c];
  unsigned tu = *(const unsigned*)&tbuf[(size_t)d * KP + c];
  float tx = __uint_as_float(tu << 16);
  float ty = __uint_as_float(tu & 0xffff0000u);
  float tx2 = 0.f, ty2 = 0.f;
  if (tl) {
    unsigned tu2 = *(const unsigned*)&tbuf[(size_t)d * KP + c2];
    tx2 = __uint_as_float(tu2 << 16);
    ty2 = __uint_as_float(tu2 & 0xffff0000u);
  }
  int beg = offsets[d], end = offsets[d + 1];
  float m = -INFINITY, l = 0.f;
  float ax = 0.f, ay = 0.f, axe = 0.f, aye = 0.f, axe2 = 0.f, aye2 = 0.f;
  for (int i = beg; i < end; ++i) {
    int e = ce[i], s = cs[i];
    unsigned eu = *(const unsigned*)&ecomb[(size_t)e * KP + c];
    float e0 = __uint_as_float(eu << 16);
    float e1 = __uint_as_float(eu & 0xffff0000u);
    float e2 = 0.f, e3 = 0.f;
    if (tl) {
      unsigned eu2 = *(const unsigned*)&ecomb[(size_t)e * KP + c2];
      e2 = __uint_as_float(eu2 << 16);
      e3 = __uint_as_float(eu2 & 0xffff0000u);
    }
    float2 kv = *(const float2*)&kbuf[(size_t)s * 128 + c];
    float2 vv = *(const float2*)&vbuf[(size_t)s * 128 + c];
    float p = qv.x * kv.x + qv.y * kv.y + tx * e0 + ty * e1 + tx2 * e2 + ty2 * e3;
    #pragma unroll
    for (int off = 1; off < 64; off <<= 1) p += __shfl_xor(p, off, 64);
    float alpha = p * 0.08838834764831845f;  // 1/sqrt(128)
    float mn = fmaxf(m, alpha);
    float scale = __expf(m - mn);            // first iter: exp(-inf)=0
    float w = __expf(alpha - mn);
    ax = ax * scale + vv.x * w;   ay = ay * scale + vv.y * w;
    axe = axe * scale + e0 * w;   aye = aye * scale + e1 * w;
    axe2 = axe2 * scale + e2 * w; aye2 = aye2 * scale + e3 * w;
    l = l * scale + w;
    m = mn;
  }
  int deg = end - beg;
  float inv = (deg > 0) ? 1.0f / (l * (float)deg) : 0.0f;
  float2 sk = *(const float2*)&accVS[(size_t)d * 128 + c];
  *(float2*)&accVS[(size_t)d * 128 + c] = make_float2(ax * inv + sk.x, ay * inv + sk.y);
  ushort2 oe; oe.x = f2bf(axe * inv); oe.y = f2bf(aye * inv);
  *(ushort2*)&accE[(size_t)d * KP + c] = oe;
  if (tl) {
    ushort2 oe2; oe2.x = f2bf(axe2 * inv); oe2.y = f2bf(aye2 * inv);
    *(ushort2*)&accE[(size_t)d * KP + c2] = oe2;
  }
}

extern "C" void kernel_launch(void* const* d_in, const int* in_sizes, int n_in,
                              void* d_out, int out_size, void* d_ws, size_t ws_size,
                              hipStream_t stream) {
  const float* var_learned = (const float*)d_in[0];
  const float* var_lp      = (const float*)d_in[1];
  const float* con_learned = (const float*)d_in[2];
  const float* con_lp      = (const float*)d_in[3];
  const float* edge_learned= (const float*)d_in[4];
  const float* lo          = (const float*)d_in[5];
  const float* hi          = (const float*)d_in[6];
  const float* dm          = (const float*)d_in[7];
  const float* wo          = (const float*)d_in[8];
  const float* cu_Wq = (const float*)d_in[9],  *cu_bq = (const float*)d_in[10];
  const float* cu_Wk = (const float*)d_in[11], *cu_bk = (const float*)d_in[12];
  const float* cu_Wv = (const float*)d_in[13], *cu_bv = (const float*)d_in[14];
  const float* cu_We = (const float*)d_in[15];
  const float* cu_Ws = (const float*)d_in[16], *cu_bs = (const float*)d_in[17];
  const float* vu_Wq = (const float*)d_in[18], *vu_bq = (const float*)d_in[19];
  const float* vu_Wk = (const float*)d_in[20], *vu_bk = (const float*)d_in[21];
  const float* vu_Wv = (const float*)d_in[22], *vu_bv = (const float*)d_in[23];
  const float* vu_We = (const float*)d_in[24];
  const float* vu_Ws = (const float*)d_in[25], *vu_bs = (const float*)d_in[26];
  const float* eu_vW1 = (const float*)d_in[27], *eu_vb1 = (const float*)d_in[28];
  const float* eu_vW2 = (const float*)d_in[29], *eu_vb2 = (const float*)d_in[30];
  const float* eu_cW1 = (const float*)d_in[31], *eu_cb1 = (const float*)d_in[32];
  const float* eu_cW2 = (const float*)d_in[33], *eu_cb2 = (const float*)d_in[34];
  const float* eu_eW1 = (const float*)d_in[35], *eu_eb1 = (const float*)d_in[36];
  const float* eu_eW2 = (const float*)d_in[37], *eu_eb2 = (const float*)d_in[38];
  const int* eiv = (const int*)d_in[39];
  const int* eic = (const int*)d_in[40];

  float* out_var  = (float*)d_out;
  float* out_con  = out_var + (size_t)NVV * 128;
  float* out_edge = out_con + (size_t)NCC * 128;

  // ---- workspace arena ----
  char* w = (char*)d_ws;
  auto alloc = [&](size_t bytes) { char* p = w; w += (bytes + 255) & ~(size_t)255; return p; };
  unsigned short* edge_comb_bf = (unsigned short*)alloc((size_t)NEE * KP * 2);  // 80MB
  unsigned short* var_comb_bf = (unsigned short*)alloc((size_t)NVV * KP * 2);
  unsigned short* con_comb_bf = (unsigned short*)alloc((size_t)NCC * KP * 2);
  unsigned short* q_bf    = (unsigned short*)alloc((size_t)NVV * KP * 2);
  unsigned short* t_bf    = (unsigned short*)alloc((size_t)NVV * KP * 2);
  unsigned short* accE_bf = (unsigned short*)alloc((size_t)NVV * KP * 2);
  float* bufV1 = (float*)alloc((size_t)NVV * 128 * 4);
  float* bufV2 = (float*)alloc((size_t)NVV * 128 * 4);
  float* bufC1 = (float*)alloc((size_t)NCC * 128 * 4);
  float* bufC2 = (float*)alloc((size_t)NCC * 128 * 4);
  unsigned short* WTbase = (unsigned short*)alloc((size_t)20 * 160 * KP * 2);
  int* countsC = (int*)alloc((size_t)NCC * 4);
  int* countsV = (int*)alloc((size_t)NVV * 4);
  int* offC = (int*)alloc((size_t)(NCC + 1) * 4);
  int* curC = (int*)alloc((size_t)NCC * 4);
  int* offV = (int*)alloc((size_t)(NVV + 1) * 4);
  int* curV = (int*)alloc((size_t)NVV * 4);
  int* ceA = (int*)alloc((size_t)NEE * 4);  // conv A (dst=con): edge ids
  int* csA = (int*)alloc((size_t)NEE * 4);  //                   src (var) ids
  int* ceB = (int*)alloc((size_t)NEE * 4);  // conv B (dst=var)
  int* csB = (int*)alloc((size_t)NEE * 4);
  (void)ws_size; (void)in_sizes; (void)n_in; (void)out_size;

  unsigned short* WT[20];
  for (int i = 0; i < 20; ++i) WT[i] = WTbase + (size_t)i * 160 * KP;
  WJobs jobs;
  const float* Wsrc[20] = {cu_Wq, cu_Wk, cu_Wv, cu_We, cu_Ws,
                           vu_Wq, vu_Wk, vu_Wv, vu_We, vu_Ws,
                           eu_vW1, eu_vW2, eu_cW1, eu_cW2,
                           eu_eW1, eu_eW1 + 136 * 128, eu_eW1 + 264 * 128, eu_eW2,
                           cu_We, vu_We};
  const int Ksrc[20] = {144, 144, 144, 136, 144, 144, 144, 144, 136, 144,
                        144, 128, 144, 128, 136, 128, 128, 128, 128, 128};
  const int Tsrc[20] = {1,1,1,1,1, 1,1,1,1,1, 1,1,1,1, 1,1,1,1, 0,0};
  for (int i = 0; i < 20; ++i) {
    jobs.W[i] = Wsrc[i]; jobs.O[i] = WT[i]; jobs.K[i] = Ksrc[i]; jobs.TR[i] = Tsrc[i];
  }

  const int T = 256;
  const int NBC = (NCC + 127) / 128;   // 98
  const int NBV = (NVV + 127) / 128;   // 196

  // ---- pre-passes ----
  build_node_bf<<<(NVV * 40 + T - 1) / T, T, 0, stream>>>(var_learned, var_lp, var_comb_bf, NVV);
  build_node_bf<<<(NCC * 40 + T - 1) / T, T, 0, stream>>>(con_learned, con_lp, con_comb_bf, NCC);
  build_edge_bf<<<(NEE * 40 + T - 1) / T, T, 0, stream>>>(edge_learned, lo, hi, dm, wo, edge_comb_bf);
  convert_weights<<<20 * 100, T, 0, stream>>>(jobs);

  // ---- CSR builds ----
  zero2<<<(NVV + T - 1) / T, T, 0, stream>>>(countsC, NCC, countsV, NVV);
  hist2<<<(NEE + T - 1) / T, T, 0, stream>>>(eic, countsC, eiv, countsV, NEE);
  csr_scan<<<1, 256, 0, stream>>>(countsC, offC, curC, NCC);
  csr_scan<<<1, 256, 0, stream>>>(countsV, offV, curV, NVV);
  csr_scatter<<<(NEE + T - 1) / T, T, 0, stream>>>(eic, eiv, curC, ceA, csA, NEE);
  csr_scatter<<<(NEE + T - 1) / T, T, 0, stream>>>(eiv, eic, curV, ceB, csB, NEE);

  // ================= Stage A: con update (src=var, dst=con) =================
  {
    GBatch b{};
    b.j[0] = {con_comb_bf, WT[0], cu_bq, nullptr, bufC1, q_bf, KP, 1, NCC, 0};  // q_c
    b.j[1] = {con_comb_bf, WT[4], cu_bs, nullptr, bufC2, nullptr, 0, 0, NCC, 0};// skip_c
    b.j[2] = {var_comb_bf, WT[1], cu_bk, nullptr, bufV1, nullptr, 0, 0, NVV, 0};// k_v
    b.j[3] = {var_comb_bf, WT[2], cu_bv, nullptr, bufV2, nullptr, 0, 0, NVV, 0};// v_v
    b.start[0] = 0; b.start[1] = NBC; b.start[2] = 2 * NBC; b.start[3] = 2 * NBC + NBV;
    b.njobs = 4;
    gemm_batch<<<2 * NBC + 2 * NBV, 256, 0, stream>>>(b);
  }
  gemm_t<<<NBC, 256, 0, stream>>>(q_bf, WT[18], t_bf, NCC);   // t_c = We @ q_c
  fused_attn<<<(NCC + 3) / 4, 256, 0, stream>>>(bufC1, bufV1, bufV2, t_bf, edge_comb_bf,
                                                offC, ceA, csA, bufC2, accE_bf, NCC);
  {
    GBatch b{};
    b.j[0] = {accE_bf, WT[3], nullptr, bufC2, out_con, con_comb_bf, KP, 0, NCC, 1};
    b.start[0] = 0; b.njobs = 1;
    gemm_batch<<<NBC, 256, 0, stream>>>(b);    // con_new = relu(accE@We + accVS)
  }

  // ================= Stage B: var update (src=new con, dst=var) =================
  {
    GBatch b{};
    b.j[0] = {var_comb_bf, WT[5], vu_bq, nullptr, bufV1, q_bf, KP, 1, NVV, 0};  // q_v
    b.j[1] = {var_comb_bf, WT[9], vu_bs, nullptr, bufV2, nullptr, 0, 0, NVV, 0};// skip_v
    b.j[2] = {con_comb_bf, WT[6], vu_bk, nullptr, bufC1, nullptr, 0, 0, NCC, 0};// k_c
    b.j[3] = {con_comb_bf, WT[7], vu_bv, nullptr, bufC2, nullptr, 0, 0, NCC, 0};// v_c
    b.start[0] = 0; b.start[1] = NBV; b.start[2] = 2 * NBV; b.start[3] = 2 * NBV + NBC;
    b.njobs = 4;
    gemm_batch<<<2 * NBV + 2 * NBC, 256, 0, stream>>>(b);
  }
  gemm_t<<<NBV, 256, 0, stream>>>(q_bf, WT[19], t_bf, NVV);   // t_v = We @ q_v
  fused_attn<<<(NVV + 3) / 4, 256, 0, stream>>>(bufV1, bufC1, bufC2, t_bf, edge_comb_bf,
                                                offV, ceB, csB, bufV2, accE_bf, NVV);
  {
    GBatch b{};
    b.j[0] = {accE_bf, WT[8], nullptr, bufV2, out_var, var_comb_bf, KP, 0, NVV, 1};
    b.start[0] = 0; b.njobs = 1;
    gemm_batch<<<NBV, 256, 0, stream>>>(b);    // var_new = relu(accE@We + accVS)
  }

  // ================= Edge stage (fully chained) =================
  gemm_chain<<<NBV, 256, 0, stream>>>(
      var_comb_bf, WT[10], eu_vb1, nullptr, nullptr, nullptr, nullptr,
      WT[11], eu_vb2, WT[15], nullptr, bufV1, NVV, 0);          // vcW
  gemm_chain<<<NBC, 256, 0, stream>>>(
      con_comb_bf, WT[12], eu_cb1, nullptr, nullptr, nullptr, nullptr,
      WT[13], eu_cb2, WT[16], nullptr, bufC1, NCC, 0);          // ccW
  gemm_chain<<<(NEE + 127) / 128, 256, 0, stream>>>(
      edge_comb_bf, WT[14], eu_eb1, bufV1, bufC1, eiv, eic,
      WT[17], eu_eb2, nullptr, nullptr, out_edge, NEE, 1);      // edge_new
}

// Round 3
// 848.625 us; speedup vs baseline: 1.3911x; 1.1859x over previous
//
#include <hip/hip_runtime.h>
#include <math.h>

#define NVV 25000
#define NCC 12500
#define NEE 250000
#define KP 160   // padded K for all bf16 GEMM inputs (covers K=128,136,144)

typedef short bf16x8 __attribute__((ext_vector_type(8)));
typedef float f32x4 __attribute__((ext_vector_type(4)));

// ---------- helpers ----------
__device__ __forceinline__ unsigned short f2bf(float f) {  // RNE fp32->bf16
  unsigned u = __float_as_uint(f);
  u += 0x7fffu + ((u >> 16) & 1u);
  return (unsigned short)(u >> 16);
}
__device__ __forceinline__ float bf2f(unsigned short u) {
  return __uint_as_float((unsigned)u << 16);
}
__device__ __forceinline__ void gll16(const unsigned short* g, unsigned short* l) {
  __builtin_amdgcn_global_load_lds(
      (const __attribute__((address_space(1))) unsigned int*)(const void*)g,
      (__attribute__((address_space(3))) unsigned int*)(void*)l, 16, 0, 0);
}

// Stage a 64-row x 160-k bf16 strip (20KB) into LDS chunk layout [kk][row64][32].
// 5 x global_load_lds_dwordx4 per thread, contiguous 320B-per-row consumption.
__device__ __forceinline__ void stage_rows64(const unsigned short* __restrict__ X,
                                             unsigned short* As, int row0, int N,
                                             int wave, int lane) {
  #pragma unroll
  for (int j = 0; j < 5; ++j) {
    int inst = wave * 5 + j;                 // 0..19
    int L = inst * 1024 + lane * 16;         // byte offset in As
    int kk = L >> 12;                        // 4096B per chunk (64 rows x 64B)
    int r = (L >> 6) & 63;
    int ks = (L & 63) >> 1;
    int grow = row0 + r; if (grow >= N) grow = N - 1;
    gll16(X + (size_t)grow * KP + kk * 32 + ks, As + inst * 512);
  }
}

template <int MI, int NI>
__device__ __forceinline__ void zero_acc(f32x4 (&acc)[MI][NI]) {
  #pragma unroll
  for (int mi = 0; mi < MI; ++mi)
    #pragma unroll
    for (int ni = 0; ni < NI; ++ni) {
      acc[mi][ni][0] = 0.f; acc[mi][ni][1] = 0.f;
      acc[mi][ni][2] = 0.f; acc[mi][ni][3] = 0.f;
    }
}

// One K-chunk (32) of MFMA: A fragments from LDS (64-row chunks), B fragments
// straight from global (weights are a 40KB L2-hot table shared by all blocks).
template <int MI, int NI>
__device__ __forceinline__ void chunk_mfma_g(const unsigned short* As,
                                             const unsigned short* __restrict__ WT,
                                             f32x4 (&acc)[MI][NI], int kk,
                                             int wm, int wn, int fr, int fq) {
  bf16x8 av[MI], bv[NI];
  #pragma unroll
  for (int mi = 0; mi < MI; ++mi)
    av[mi] = *(const bf16x8*)&As[kk * 2048 + (wm + mi * 16 + fr) * 32 + fq * 8];
  #pragma unroll
  for (int ni = 0; ni < NI; ++ni)
    bv[ni] = *(const bf16x8*)&WT[(size_t)(wn + ni * 16 + fr) * KP + kk * 32 + fq * 8];
  #pragma unroll
  for (int mi = 0; mi < MI; ++mi)
    #pragma unroll
    for (int ni = 0; ni < NI; ++ni)
      acc[mi][ni] = __builtin_amdgcn_mfma_f32_16x16x32_bf16(av[mi], bv[ni],
                                                            acc[mi][ni], 0, 0, 0);
}

// ---------- batched bf16 MFMA GEMM: out[N,128] = X[N,160] @ WT^T ----------
struct GJob {
  const unsigned short* X; const unsigned short* WT;
  const float* bias; const float* addf;
  float* outf; unsigned short* outb;
  int outb_stride, pad_flag, N, relu_flag;
};
struct GBatch { GJob j[4]; int start[4]; int njobs; };

__global__ __launch_bounds__(256, 8) void gemm_batch(GBatch B) {
  int job = 0;
  #pragma unroll
  for (int t = 1; t < 4; ++t)
    if (t < B.njobs && (int)blockIdx.x >= B.start[t]) job = t;
  GJob g = B.j[job];
  __shared__ unsigned short As[5 * 64 * 32];   // 20 KB
  const int tid = threadIdx.x;
  const int lane = tid & 63, wave = tid >> 6;
  const int row0 = (blockIdx.x - B.start[job]) * 64;
  const int wm = (wave & 1) * 32, wn = (wave >> 1) * 64;
  const int fr = lane & 15, fq = lane >> 4;

  stage_rows64(g.X, As, row0, g.N, wave, lane);
  f32x4 acc[2][4];
  zero_acc<2, 4>(acc);
  __syncthreads();
  #pragma unroll
  for (int kk = 0; kk < 5; ++kk) chunk_mfma_g<2, 4>(As, g.WT, acc, kk, wm, wn, fr, fq);

  #pragma unroll
  for (int mi = 0; mi < 2; ++mi) {
    #pragma unroll
    for (int ni = 0; ni < 4; ++ni) {
      int gcol = wn + ni * 16 + fr;
      float bvv = g.bias ? g.bias[gcol] : 0.0f;
      #pragma unroll
      for (int r = 0; r < 4; ++r) {
        int grow = row0 + wm + mi * 16 + fq * 4 + r;
        if (grow < g.N) {
          float o = acc[mi][ni][r] + bvv;
          if (g.addf) o += g.addf[(size_t)grow * 128 + gcol];
          if (g.relu_flag) o = fmaxf(o, 0.f);
          if (g.outf) g.outf[(size_t)grow * 128 + gcol] = o;
          if (g.outb) g.outb[(size_t)grow * g.outb_stride + gcol] = f2bf(o);
        }
      }
    }
    if (g.outb && g.pad_flag && wn == 0) {
      #pragma unroll
      for (int r = 0; r < 4; ++r) {
        int grow = row0 + wm + mi * 16 + fq * 4 + r;
        if (grow < g.N)
          for (int pc = 128 + fr; pc < g.outb_stride; pc += 16)
            g.outb[(size_t)grow * g.outb_stride + pc] = 0;
      }
    }
  }
}

// ---------- NI=5 GEMM: t[N,160] = X[N,160(K=128)] @ W'[160,K], bf16 out ----
__global__ __launch_bounds__(256, 4) void gemm_t(
    const unsigned short* __restrict__ X, const unsigned short* __restrict__ WT,
    unsigned short* __restrict__ outb, int N) {
  __shared__ unsigned short As[5 * 64 * 32];
  const int tid = threadIdx.x;
  const int lane = tid & 63, wave = tid >> 6;
  const int row0 = blockIdx.x * 64;
  const int wm = (wave & 1) * 32, wn = (wave >> 1) * 80;
  const int fr = lane & 15, fq = lane >> 4;

  stage_rows64(X, As, row0, N, wave, lane);
  f32x4 acc[2][5];
  zero_acc<2, 5>(acc);
  __syncthreads();
  #pragma unroll
  for (int kk = 0; kk < 5; ++kk) chunk_mfma_g<2, 5>(As, WT, acc, kk, wm, wn, fr, fq);

  #pragma unroll
  for (int mi = 0; mi < 2; ++mi)
    #pragma unroll
    for (int ni = 0; ni < 5; ++ni) {
      int gcol = wn + ni * 16 + fr;
      #pragma unroll
      for (int r = 0; r < 4; ++r) {
        int grow = row0 + wm + mi * 16 + fq * 4 + r;
        if (grow < N) outb[(size_t)grow * KP + gcol] = f2bf(acc[mi][ni][r]);
      }
    }
}

// ---------- chained GEMM: X@W1(+b1,+gather,relu) -> @W2 -> [@W3] ----------
// 64-row tile; stage-k output feeds stage-k+1 through LDS (bf16, chunk layout).
__global__ __launch_bounds__(256, 4) void gemm_chain(
    const unsigned short* __restrict__ X,
    const unsigned short* __restrict__ W1, const float* __restrict__ b1,
    const unsigned short* __restrict__ gA, const unsigned short* __restrict__ gB,
    const int* __restrict__ giA, const int* __restrict__ giB,
    const unsigned short* __restrict__ W2, const float* __restrict__ b2,
    const unsigned short* __restrict__ W3, const float* __restrict__ b3,
    float* __restrict__ outf, unsigned short* __restrict__ outw,
    int N, int relu_last) {
  __shared__ unsigned short As[5 * 64 * 32];   // 20 KB, reused for T2
  const int tid = threadIdx.x;
  const int lane = tid & 63, wave = tid >> 6;
  const int row0 = blockIdx.x * 64;
  const int wm = (wave & 1) * 32, wn = (wave >> 1) * 64;
  const int fr = lane & 15, fq = lane >> 4;

  // ---- stage 1 ----
  stage_rows64(X, As, row0, N, wave, lane);
  f32x4 acc[2][4];
  zero_acc<2, 4>(acc);
  __syncthreads();
  #pragma unroll
  for (int kk = 0; kk < 5; ++kk) chunk_mfma_g<2, 4>(As, W1, acc, kk, wm, wn, fr, fq);

  // ---- epilogue 1 -> T2 (reuse As) ----
  __syncthreads();                       // all stage-1 LDS reads finished
  #pragma unroll
  for (int mi = 0; mi < 2; ++mi) {
    #pragma unroll
    for (int ni = 0; ni < 4; ++ni) {
      int col = wn + ni * 16 + fr;
      float bvv = b1 ? b1[col] : 0.0f;
      #pragma unroll
      for (int r = 0; r < 4; ++r) {
        int row = wm + mi * 16 + fq * 4 + r;
        int grow = row0 + row;
        int gi = (grow < N) ? grow : (N - 1);
        float o = acc[mi][ni][r] + bvv;
        if (gA) o += bf2f(gA[(size_t)giA[gi] * 128 + col]) +
                     bf2f(gB[(size_t)giB[gi] * 128 + col]);
        o = fmaxf(o, 0.f);
        As[(col >> 5) * 2048 + row * 32 + (col & 31)] = f2bf(o);
      }
    }
  }
  zero_acc<2, 4>(acc);
  __syncthreads();                       // T2 visible

  // ---- stage 2 ----
  #pragma unroll
  for (int kk = 0; kk < 4; ++kk) chunk_mfma_g<2, 4>(As, W2, acc, kk, wm, wn, fr, fq);

  if (W3) {
    __syncthreads();
    #pragma unroll
    for (int mi = 0; mi < 2; ++mi) {
      #pragma unroll
      for (int ni = 0; ni < 4; ++ni) {
        int col = wn + ni * 16 + fr;
        float bvv = b2 ? b2[col] : 0.0f;
        #pragma unroll
        for (int r = 0; r < 4; ++r) {
          int row = wm + mi * 16 + fq * 4 + r;
          float o = fmaxf(acc[mi][ni][r] + bvv, 0.f);
          As[(col >> 5) * 2048 + row * 32 + (col & 31)] = f2bf(o);
        }
      }
    }
    zero_acc<2, 4>(acc);
    __syncthreads();
    #pragma unroll
    for (int kk = 0; kk < 4; ++kk) chunk_mfma_g<2, 4>(As, W3, acc, kk, wm, wn, fr, fq);
    #pragma unroll
    for (int mi = 0; mi < 2; ++mi)
      #pragma unroll
      for (int ni = 0; ni < 4; ++ni) {
        int gcol = wn + ni * 16 + fr;
        float bvv = b3 ? b3[gcol] : 0.0f;
        #pragma unroll
        for (int r = 0; r < 4; ++r) {
          int grow = row0 + wm + mi * 16 + fq * 4 + r;
          if (grow < N) {
            float o = acc[mi][ni][r] + bvv;
            if (relu_last) o = fmaxf(o, 0.f);
            if (outw) outw[(size_t)grow * 128 + gcol] = f2bf(o);
            else      outf[(size_t)grow * 128 + gcol] = o;
          }
        }
      }
  } else {
    #pragma unroll
    for (int mi = 0; mi < 2; ++mi)
      #pragma unroll
      for (int ni = 0; ni < 4; ++ni) {
        int gcol = wn + ni * 16 + fr;
        float bvv = b2 ? b2[gcol] : 0.0f;
        #pragma unroll
        for (int r = 0; r < 4; ++r) {
          int grow = row0 + wm + mi * 16 + fq * 4 + r;
          if (grow < N) {
            float o = acc[mi][ni][r] + bvv;
            if (relu_last) o = fmaxf(o, 0.f);
            if (outw) outw[(size_t)grow * 128 + gcol] = f2bf(o);
            else      outf[(size_t)grow * 128 + gcol] = o;
          }
        }
      }
  }
}

// ---------- build bf16 combined features ----------
__global__ void build_node_bf(const float* __restrict__ learned, const float* __restrict__ lp,
                              unsigned short* __restrict__ out, int N) {
  int idx = blockIdx.x * blockDim.x + threadIdx.x;
  if (idx >= N * 40) return;
  int row = idx / 40, c4 = idx - row * 40;
  int c = c4 * 4;
  ushort4 o;
  if (c4 < 32) {
    const float* p = learned + (size_t)row * 128 + c;
    o.x = f2bf(p[0]); o.y = f2bf(p[1]); o.z = f2bf(p[2]); o.w = f2bf(p[3]);
  } else if (c4 < 36) {
    const float* p = lp + (size_t)row * 16 + (c - 128);
    o.x = f2bf(p[0]); o.y = f2bf(p[1]); o.z = f2bf(p[2]); o.w = f2bf(p[3]);
  } else { o.x = o.y = o.z = o.w = 0; }
  *(ushort4*)&out[(size_t)row * KP + c] = o;
}

__global__ void build_edge_bf(const float* __restrict__ el, const float* __restrict__ lo,
                              const float* __restrict__ hi, const float* __restrict__ dm,
                              const float* __restrict__ wo, unsigned short* __restrict__ out) {
  int idx = blockIdx.x * blockDim.x + threadIdx.x;
  if (idx >= NEE * 40) return;
  int row = idx / 40, c4 = idx - row * 40;
  int c = c4 * 4;
  ushort4 o;
  if (c4 < 32) {
    const float* p = el + (size_t)row * 128 + c;
    o.x = f2bf(p[0]); o.y = f2bf(p[1]); o.z = f2bf(p[2]); o.w = f2bf(p[3]);
  } else if (c4 == 32) {
    o.x = f2bf(lo[row]); o.y = f2bf(hi[row]); o.z = f2bf(dm[row]);
    o.w = f2bf(wo[(size_t)row * 5 + 0]);
  } else if (c4 == 33) {
    const float* p = wo + (size_t)row * 5;
    o.x = f2bf(p[1]); o.y = f2bf(p[2]); o.z = f2bf(p[3]); o.w = f2bf(p[4]);
  } else { o.x = o.y = o.z = o.w = 0; }
  *(ushort4*)&out[(size_t)row * KP + c] = o;
}

// ---------- weight transpose/copy + convert ----------
// TR=1: O[col][k] = W[k,col] (col<128, k<K)     — GEMM weight layout
// TR=0: O[i][o]   = W[i,o]   (i<136, o<K=128)   — straight copy (We for t-GEMM)
struct WJobs {
  const float* W[20];
  unsigned short* O[20];
  int K[20];
  int TR[20];
};
__global__ void convert_weights(WJobs j) {
  int b = blockIdx.x;
  int job = b / 100;
  int i = (b - job * 100) * 256 + threadIdx.x;   // 0 .. 160*KP
  int col = i / KP;
  int k = i - col * KP;
  float v = 0.f;
  if (j.TR[job]) { if (col < 128 && k < j.K[job]) v = j.W[job][(size_t)k * 128 + col]; }
  else           { if (col < 136 && k < j.K[job]) v = j.W[job][(size_t)col * 128 + k]; }
  j.O[job][(size_t)col * KP + k] = f2bf(v);
}

// ---------- CSR construction ----------
__global__ void zero2(int* __restrict__ a, int na, int* __restrict__ b, int nb) {
  int i = blockIdx.x * blockDim.x + threadIdx.x;
  if (i < na) a[i] = 0;
  if (i < nb) b[i] = 0;
}
__global__ void hist2(const int* __restrict__ dc, int* __restrict__ cc,
                      const int* __restrict__ dv, int* __restrict__ cv, int nE) {
  int e = blockIdx.x * blockDim.x + threadIdx.x;
  if (e >= nE) return;
  atomicAdd(&cc[dc[e]], 1);
  atomicAdd(&cv[dv[e]], 1);
}
// single block 256 threads
__global__ void csr_scan(const int* __restrict__ counts, int* __restrict__ offsets,
                         int* __restrict__ cursor, int n) {
  __shared__ int part[256];
  int tid = threadIdx.x;
  int chunk = (n + 255) / 256;
  int lo = tid * chunk, hi = min(n, lo + chunk);
  int s = 0;
  for (int i = lo; i < hi; ++i) s += counts[i];
  part[tid] = s;
  __syncthreads();
  if (tid == 0) {
    int run = 0;
    for (int i = 0; i < 256; ++i) { int t = part[i]; part[i] = run; run += t; }
    offsets[n] = run;
  }
  __syncthreads();
  int base = part[tid];
  for (int i = lo; i < hi; ++i) { offsets[i] = base; cursor[i] = base; base += counts[i]; }
}
__global__ void csr_scatter(const int* __restrict__ dst, const int* __restrict__ src,
                            int* __restrict__ cursor, int* __restrict__ ce,
                            int* __restrict__ cs, int nE) {
  int e = blockIdx.x * blockDim.x + threadIdx.x;
  if (e >= nE) return;
  int pos = atomicAdd(&cursor[dst[e]], 1);
  ce[pos] = e;
  cs[pos] = src[e];
}

// ---------- fused flash-style segment attention: one wave per dst ----------
// ee eliminated algebraically:  q·ee = t·e with t = We@q (bf16, [Nd,160]);
// Σ a·ee = (Σ a·e)@We  -> accumulate 136-dim weighted edge sum, transform later.
// k/v are bf16 [Ns,128]. 2-edge unrolled loop for load-level parallelism.
__global__ void fused_attn(
    const float* __restrict__ qbuf, const unsigned short* __restrict__ kbuf,
    const unsigned short* __restrict__ vbuf, const unsigned short* __restrict__ tbuf,
    const unsigned short* __restrict__ ecomb,
    const int* __restrict__ offsets, const int* __restrict__ ce,
    const int* __restrict__ cs, float* __restrict__ accVS,
    unsigned short* __restrict__ accE, int Nd) {
  int d = blockIdx.x * 4 + (threadIdx.x >> 6);
  if (d >= Nd) return;
  int lane = threadIdx.x & 63;
  int c = lane * 2;
  bool tl = (lane < 16);
  int c2 = 128 + c;                     // tail cols for lanes 0..15
  float2 qv = *(const float2*)&qbuf[(size_t)d * 128 + c];
  unsigned tu = *(const unsigned*)&tbuf[(size_t)d * KP + c];
  float tx = __uint_as_float(tu << 16);
  float ty = __uint_as_float(tu & 0xffff0000u);
  float tx2 = 0.f, ty2 = 0.f;
  if (tl) {
    unsigned tu2 = *(const unsigned*)&tbuf[(size_t)d * KP + c2];
    tx2 = __uint_as_float(tu2 << 16);
    ty2 = __uint_as_float(tu2 & 0xffff0000u);
  }
  int beg = offsets[d], end = offsets[d + 1];
  float m = -INFINITY, l = 0.f;
  float ax = 0.f, ay = 0.f, axe = 0.f, aye = 0.f, axe2 = 0.f, aye2 = 0.f;
  const float SC = 0.08838834764831845f;  // 1/sqrt(128)
  int i = beg;
  for (; i + 1 < end; i += 2) {
    int ea = ce[i], sa = cs[i];
    int eb = ce[i + 1], sb = cs[i + 1];
    unsigned eua = *(const unsigned*)&ecomb[(size_t)ea * KP + c];
    unsigned eub = *(const unsigned*)&ecomb[(size_t)eb * KP + c];
    unsigned kua = *(const unsigned*)&kbuf[(size_t)sa * 128 + c];
    unsigned kub = *(const unsigned*)&kbuf[(size_t)sb * 128 + c];
    unsigned vua = *(const unsigned*)&vbuf[(size_t)sa * 128 + c];
    unsigned vub = *(const unsigned*)&vbuf[(size_t)sb * 128 + c];
    float a0 = __uint_as_float(eua << 16), a1 = __uint_as_float(eua & 0xffff0000u);
    float b0 = __uint_as_float(eub << 16), b1 = __uint_as_float(eub & 0xffff0000u);
    float a2 = 0.f, a3 = 0.f, b2 = 0.f, b3 = 0.f;
    if (tl) {
      unsigned eua2 = *(const unsigned*)&ecomb[(size_t)ea * KP + c2];
      unsigned eub2 = *(const unsigned*)&ecomb[(size_t)eb * KP + c2];
      a2 = __uint_as_float(eua2 << 16); a3 = __uint_as_float(eua2 & 0xffff0000u);
      b2 = __uint_as_float(eub2 << 16); b3 = __uint_as_float(eub2 & 0xffff0000u);
    }
    float pa = qv.x * __uint_as_float(kua << 16) + qv.y * __uint_as_float(kua & 0xffff0000u)
             + tx * a0 + ty * a1 + tx2 * a2 + ty2 * a3;
    float pb = qv.x * __uint_as_float(kub << 16) + qv.y * __uint_as_float(kub & 0xffff0000u)
             + tx * b0 + ty * b1 + tx2 * b2 + ty2 * b3;
    #pragma unroll
    for (int off = 1; off < 64; off <<= 1) {
      pa += __shfl_xor(pa, off, 64);
      pb += __shfl_xor(pb, off, 64);
    }
    // sequential online-softmax updates (a then b)
    {
      float alpha = pa * SC;
      float mn = fmaxf(m, alpha);
      float scale = __expf(m - mn);
      float w = __expf(alpha - mn);
      ax = ax * scale + __uint_as_float(vua << 16) * w;
      ay = ay * scale + __uint_as_float(vua & 0xffff0000u) * w;
      axe = axe * scale + a0 * w;   aye = aye * scale + a1 * w;
      axe2 = axe2 * scale + a2 * w; aye2 = aye2 * scale + a3 * w;
      l = l * scale + w; m = mn;
    }
    {
      float alpha = pb * SC;
      float mn = fmaxf(m, alpha);
      float scale = __expf(m - mn);
      float w = __expf(alpha - mn);
      ax = ax * scale + __uint_as_float(vub << 16) * w;
      ay = ay * scale + __uint_as_float(vub & 0xffff0000u) * w;
      axe = axe * scale + b0 * w;   aye = aye * scale + b1 * w;
      axe2 = axe2 * scale + b2 * w; aye2 = aye2 * scale + b3 * w;
      l = l * scale + w; m = mn;
    }
  }
  if (i < end) {
    int e = ce[i], s = cs[i];
    unsigned eu = *(const unsigned*)&ecomb[(size_t)e * KP + c];
    float e0 = __uint_as_float(eu << 16);
    float e1 = __uint_as_float(eu & 0xffff0000u);
    float e2 = 0.f, e3 = 0.f;
    if (tl) {
      unsigned eu2 = *(const unsigned*)&ecomb[(size_t)e * KP + c2];
      e2 = __uint_as_float(eu2 << 16);
      e3 = __uint_as_float(eu2 & 0xffff0000u);
    }
    unsigned ku = *(const unsigned*)&kbuf[(size_t)s * 128 + c];
    unsigned vu = *(const unsigned*)&vbuf[(size_t)s * 128 + c];
    float p = qv.x * __uint_as_float(ku << 16) + qv.y * __uint_as_float(ku & 0xffff0000u)
            + tx * e0 + ty * e1 + tx2 * e2 + ty2 * e3;
    #pragma unroll
    for (int off = 1; off < 64; off <<= 1) p += __shfl_xor(p, off, 64);
    float alpha = p * SC;
    float mn = fmaxf(m, alpha);
    float scale = __expf(m - mn);
    float w = __expf(alpha - mn);
    ax = ax * scale + __uint_as_float(vu << 16) * w;
    ay = ay * scale + __uint_as_float(vu & 0xffff0000u) * w;
    axe = axe * scale + e0 * w;   aye = aye * scale + e1 * w;
    axe2 = axe2 * scale + e2 * w; aye2 = aye2 * scale + e3 * w;
    l = l * scale + w; m = mn;
  }
  int deg = end - beg;
  float inv = (deg > 0) ? 1.0f / (l * (float)deg) : 0.0f;
  float2 sk = *(const float2*)&accVS[(size_t)d * 128 + c];
  *(float2*)&accVS[(size_t)d * 128 + c] = make_float2(ax * inv + sk.x, ay * inv + sk.y);
  ushort2 oe; oe.x = f2bf(axe * inv); oe.y = f2bf(aye * inv);
  *(ushort2*)&accE[(size_t)d * KP + c] = oe;
  if (tl) {
    ushort2 oe2; oe2.x = f2bf(axe2 * inv); oe2.y = f2bf(aye2 * inv);
    *(ushort2*)&accE[(size_t)d * KP + c2] = oe2;
  }
}

extern "C" void kernel_launch(void* const* d_in, const int* in_sizes, int n_in,
                              void* d_out, int out_size, void* d_ws, size_t ws_size,
                              hipStream_t stream) {
  const float* var_learned = (const float*)d_in[0];
  const float* var_lp      = (const float*)d_in[1];
  const float* con_learned = (const float*)d_in[2];
  const float* con_lp      = (const float*)d_in[3];
  const float* edge_learned= (const float*)d_in[4];
  const float* lo          = (const float*)d_in[5];
  const float* hi          = (const float*)d_in[6];
  const float* dm          = (const float*)d_in[7];
  const float* wo          = (const float*)d_in[8];
  const float* cu_Wq = (const float*)d_in[9],  *cu_bq = (const float*)d_in[10];
  const float* cu_Wk = (const float*)d_in[11], *cu_bk = (const float*)d_in[12];
  const float* cu_Wv = (const float*)d_in[13], *cu_bv = (const float*)d_in[14];
  const float* cu_We = (const float*)d_in[15];
  const float* cu_Ws = (const float*)d_in[16], *cu_bs = (const float*)d_in[17];
  const float* vu_Wq = (const float*)d_in[18], *vu_bq = (const float*)d_in[19];
  const float* vu_Wk = (const float*)d_in[20], *vu_bk = (const float*)d_in[21];
  const float* vu_Wv = (const float*)d_in[22], *vu_bv = (const float*)d_in[23];
  const float* vu_We = (const float*)d_in[24];
  const float* vu_Ws = (const float*)d_in[25], *vu_bs = (const float*)d_in[26];
  const float* eu_vW1 = (const float*)d_in[27], *eu_vb1 = (const float*)d_in[28];
  const float* eu_vW2 = (const float*)d_in[29], *eu_vb2 = (const float*)d_in[30];
  const float* eu_cW1 = (const float*)d_in[31], *eu_cb1 = (const float*)d_in[32];
  const float* eu_cW2 = (const float*)d_in[33], *eu_cb2 = (const float*)d_in[34];
  const float* eu_eW1 = (const float*)d_in[35], *eu_eb1 = (const float*)d_in[36];
  const float* eu_eW2 = (const float*)d_in[37], *eu_eb2 = (const float*)d_in[38];
  const int* eiv = (const int*)d_in[39];
  const int* eic = (const int*)d_in[40];

  float* out_var  = (float*)d_out;
  float* out_con  = out_var + (size_t)NVV * 128;
  float* out_edge = out_con + (size_t)NCC * 128;

  // ---- workspace arena ----
  char* w = (char*)d_ws;
  auto alloc = [&](size_t bytes) { char* p = w; w += (bytes + 255) & ~(size_t)255; return p; };
  unsigned short* edge_comb_bf = (unsigned short*)alloc((size_t)NEE * KP * 2);  // 80MB
  unsigned short* var_comb_bf = (unsigned short*)alloc((size_t)NVV * KP * 2);
  unsigned short* con_comb_bf = (unsigned short*)alloc((size_t)NCC * KP * 2);
  unsigned short* q_bf    = (unsigned short*)alloc((size_t)NVV * KP * 2);
  unsigned short* t_bf    = (unsigned short*)alloc((size_t)NVV * KP * 2);
  unsigned short* accE_bf = (unsigned short*)alloc((size_t)NVV * KP * 2);
  unsigned short* kv_bf   = (unsigned short*)alloc((size_t)NVV * 128 * 2);
  unsigned short* vv_bf   = (unsigned short*)alloc((size_t)NVV * 128 * 2);
  unsigned short* vc_bf   = (unsigned short*)alloc((size_t)NVV * 128 * 2);
  unsigned short* cc_bf   = (unsigned short*)alloc((size_t)NCC * 128 * 2);
  float* bufV1 = (float*)alloc((size_t)NVV * 128 * 4);
  float* bufV2 = (float*)alloc((size_t)NVV * 128 * 4);
  float* bufC1 = (float*)alloc((size_t)NCC * 128 * 4);
  float* bufC2 = (float*)alloc((size_t)NCC * 128 * 4);
  unsigned short* WTbase = (unsigned short*)alloc((size_t)20 * 160 * KP * 2);
  int* countsC = (int*)alloc((size_t)NCC * 4);
  int* countsV = (int*)alloc((size_t)NVV * 4);
  int* offC = (int*)alloc((size_t)(NCC + 1) * 4);
  int* curC = (int*)alloc((size_t)NCC * 4);
  int* offV = (int*)alloc((size_t)(NVV + 1) * 4);
  int* curV = (int*)alloc((size_t)NVV * 4);
  int* ceA = (int*)alloc((size_t)NEE * 4);  // conv A (dst=con): edge ids
  int* csA = (int*)alloc((size_t)NEE * 4);  //                   src (var) ids
  int* ceB = (int*)alloc((size_t)NEE * 4);  // conv B (dst=var)
  int* csB = (int*)alloc((size_t)NEE * 4);
  (void)ws_size; (void)in_sizes; (void)n_in; (void)out_size;

  unsigned short* WT[20];
  for (int i = 0; i < 20; ++i) WT[i] = WTbase + (size_t)i * 160 * KP;
  WJobs jobs;
  const float* Wsrc[20] = {cu_Wq, cu_Wk, cu_Wv, cu_We, cu_Ws,
                           vu_Wq, vu_Wk, vu_Wv, vu_We, vu_Ws,
                           eu_vW1, eu_vW2, eu_cW1, eu_cW2,
                           eu_eW1, eu_eW1 + 136 * 128, eu_eW1 + 264 * 128, eu_eW2,
                           cu_We, vu_We};
  const int Ksrc[20] = {144, 144, 144, 136, 144, 144, 144, 144, 136, 144,
                        144, 128, 144, 128, 136, 128, 128, 128, 128, 128};
  const int Tsrc[20] = {1,1,1,1,1, 1,1,1,1,1, 1,1,1,1, 1,1,1,1, 0,0};
  for (int i = 0; i < 20; ++i) {
    jobs.W[i] = Wsrc[i]; jobs.O[i] = WT[i]; jobs.K[i] = Ksrc[i]; jobs.TR[i] = Tsrc[i];
  }

  const int T = 256;
  const int NBC = (NCC + 63) / 64;   // 196
  const int NBV = (NVV + 63) / 64;   // 391
  const int NBE = (NEE + 63) / 64;   // 3907

  // ---- pre-passes ----
  build_node_bf<<<(NVV * 40 + T - 1) / T, T, 0, stream>>>(var_learned, var_lp, var_comb_bf, NVV);
  build_node_bf<<<(NCC * 40 + T - 1) / T, T, 0, stream>>>(con_learned, con_lp, con_comb_bf, NCC);
  build_edge_bf<<<(NEE * 40 + T - 1) / T, T, 0, stream>>>(edge_learned, lo, hi, dm, wo, edge_comb_bf);
  convert_weights<<<20 * 100, T, 0, stream>>>(jobs);

  // ---- CSR builds ----
  zero2<<<(NVV + T - 1) / T, T, 0, stream>>>(countsC, NCC, countsV, NVV);
  hist2<<<(NEE + T - 1) / T, T, 0, stream>>>(eic, countsC, eiv, countsV, NEE);
  csr_scan<<<1, 256, 0, stream>>>(countsC, offC, curC, NCC);
  csr_scan<<<1, 256, 0, stream>>>(countsV, offV, curV, NVV);
  csr_scatter<<<(NEE + T - 1) / T, T, 0, stream>>>(eic, eiv, curC, ceA, csA, NEE);
  csr_scatter<<<(NEE + T - 1) / T, T, 0, stream>>>(eiv, eic, curV, ceB, csB, NEE);

  // ================= Stage A: con update (src=var, dst=con) =================
  {
    GBatch b{};
    b.j[0] = {con_comb_bf, WT[0], cu_bq, nullptr, bufC1, q_bf, KP, 1, NCC, 0};   // q_c
    b.j[1] = {con_comb_bf, WT[4], cu_bs, nullptr, bufC2, nullptr, 0, 0, NCC, 0}; // skip_c
    b.j[2] = {var_comb_bf, WT[1], cu_bk, nullptr, nullptr, kv_bf, 128, 0, NVV, 0}; // k_v
    b.j[3] = {var_comb_bf, WT[2], cu_bv, nullptr, nullptr, vv_bf, 128, 0, NVV, 0}; // v_v
    b.start[0] = 0; b.start[1] = NBC; b.start[2] = 2 * NBC; b.start[3] = 2 * NBC + NBV;
    b.njobs = 4;
    gemm_batch<<<2 * NBC + 2 * NBV, 256, 0, stream>>>(b);
  }
  gemm_t<<<NBC, 256, 0, stream>>>(q_bf, WT[18], t_bf, NCC);   // t_c = We @ q_c
  fused_attn<<<(NCC + 3) / 4, 256, 0, stream>>>(bufC1, kv_bf, vv_bf, t_bf, edge_comb_bf,
                                                offC, ceA, csA, bufC2, accE_bf, NCC);
  {
    GBatch b{};
    b.j[0] = {accE_bf, WT[3], nullptr, bufC2, out_con, con_comb_bf, KP, 0, NCC, 1};
    b.start[0] = 0; b.njobs = 1;
    gemm_batch<<<NBC, 256, 0, stream>>>(b);    // con_new = relu(accE@We + accVS)
  }

  // ================= Stage B: var update (src=new con, dst=var) =================
  {
    GBatch b{};
    b.j[0] = {var_comb_bf, WT[5], vu_bq, nullptr, bufV1, q_bf, KP, 1, NVV, 0};   // q_v
    b.j[1] = {var_comb_bf, WT[9], vu_bs, nullptr, bufV2, nullptr, 0, 0, NVV, 0}; // skip_v
    b.j[2] = {con_comb_bf, WT[6], vu_bk, nullptr, nullptr, kv_bf, 128, 0, NCC, 0}; // k_c
    b.j[3] = {con_comb_bf, WT[7], vu_bv, nullptr, nullptr, vv_bf, 128, 0, NCC, 0}; // v_c
    b.start[0] = 0; b.start[1] = NBV; b.start[2] = 2 * NBV; b.start[3] = 2 * NBV + NBC;
    b.njobs = 4;
    gemm_batch<<<2 * NBV + 2 * NBC, 256, 0, stream>>>(b);
  }
  gemm_t<<<NBV, 256, 0, stream>>>(q_bf, WT[19], t_bf, NVV);   // t_v = We @ q_v
  fused_attn<<<(NVV + 3) / 4, 256, 0, stream>>>(bufV1, kv_bf, vv_bf, t_bf, edge_comb_bf,
                                                offV, ceB, csB, bufV2, accE_bf, NVV);
  {
    GBatch b{};
    b.j[0] = {accE_bf, WT[8], nullptr, bufV2, out_var, var_comb_bf, KP, 0, NVV, 1};
    b.start[0] = 0; b.njobs = 1;
    gemm_batch<<<NBV, 256, 0, stream>>>(b);    // var_new = relu(accE@We + accVS)
  }

  // ================= Edge stage (fully chained) =================
  gemm_chain<<<NBV, 256, 0, stream>>>(
      var_comb_bf, WT[10], eu_vb1, nullptr, nullptr, nullptr, nullptr,
      WT[11], eu_vb2, WT[15], nullptr, nullptr, vc_bf, NVV, 0);   // vcW (bf16)
  gemm_chain<<<NBC, 256, 0, stream>>>(
      con_comb_bf, WT[12], eu_cb1, nullptr, nullptr, nullptr, nullptr,
      WT[13], eu_cb2, WT[16], nullptr, nullptr, cc_bf, NCC, 0);   // ccW (bf16)
  gemm_chain<<<NBE, 256, 0, stream>>>(
      edge_comb_bf, WT[14], eu_eb1, vc_bf, cc_bf, eiv, eic,
      WT[17], eu_eb2, nullptr, nullptr, out_edge, nullptr, NEE, 1);  // edge_new
}